// Round 10
// baseline (512.544 us; speedup 1.0000x reference)
//
#include <hip/hip_runtime.h>
#include <hip/hip_bf16.h>
#include <stdint.h>
#include <cstddef>

typedef short short8 __attribute__((ext_vector_type(8)));
typedef float f32x4 __attribute__((ext_vector_type(4)));
typedef unsigned short us4 __attribute__((ext_vector_type(4)));
typedef unsigned short us8 __attribute__((ext_vector_type(8)));

#define DEV static __device__ __forceinline__

DEV unsigned short f2b(float f) {
  __hip_bfloat16 h = __float2bfloat16(f);
  return __builtin_bit_cast(unsigned short, h);
}
DEV float b2f(unsigned short u) {
  unsigned int t = ((unsigned int)u) << 16;
  return __builtin_bit_cast(float, t);
}

DEV void gload_lds16(const void* g, void* lds) {
  __builtin_amdgcn_global_load_lds((const __attribute__((address_space(1))) unsigned int*)g,
                                   (__attribute__((address_space(3))) unsigned int*)lds, 16, 0, 0);
}

// ---------------------------------------------------------------------------
// 256x256 bf16 GEMM, 8-phase schedule (T2+T3+T4+T5). Replay-proven (R5-R9).
// ---------------------------------------------------------------------------
__launch_bounds__(512, 2)
__global__ void gemm256_8ph(const unsigned short* __restrict__ A,
                            const unsigned short* __restrict__ Bt,
                            unsigned short* __restrict__ Cb,
                            int M, int N, int K)
{
  __shared__ __attribute__((aligned(16))) char lds[131072];
  const int tid = threadIdx.x;
  const int lane = tid & 63, w = tid >> 6;
  const int wr = w >> 2, wc = w & 3;
  const int g = lane >> 4, lr = lane & 15;
  const int ntile = N >> 8;
  const int nwg = gridDim.x;
  const int bid = blockIdx.x;
  const int tile = ((nwg & 7) == 0) ? ((bid & 7)*(nwg >> 3) + (bid >> 3)) : bid;
  const size_t m0 = (size_t)(tile / ntile) << 8;
  const size_t n0 = (size_t)(tile % ntile) << 8;

  const int srl = tid >> 3;
  const int sgc = ((tid & 7) ^ (srl & 7)) * 8;

#define STAGEH(X, grow0, k0, ldsoff)                                           \
  do {                                                                         \
    char* hb_ = lds + (ldsoff) + w*1024;                                       \
    gload_lds16((X) + ((grow0) + srl)*(size_t)K + (k0) + sgc, hb_);            \
    gload_lds16((X) + ((grow0) + 64 + srl)*(size_t)K + (k0) + sgc, hb_ + 8192);\
  } while (0)

#define BAR() do { __builtin_amdgcn_sched_barrier(0); __builtin_amdgcn_s_barrier(); __builtin_amdgcn_sched_barrier(0); } while (0)

  f32x4 acc[8][4] = {};
  short8 aF[4][2], bF[4][2];

  int aoff[2], boff[2];
#pragma unroll
  for (int kk = 0; kk < 2; ++kk) {
    const int sl = (((kk*4 + g) ^ (lr & 7)) * 16);
    aoff[kk] = wr*16384 + lr*128 + sl;
    boff[kk] = 32768 + (wc >> 1)*16384 + ((wc & 1)*64 + lr)*128 + sl;
  }

#define MFQ(mh, nh)                                                            \
  do {                                                                         \
    __builtin_amdgcn_s_setprio(1);                                             \
    _Pragma("unroll")                                                          \
    for (int kk = 0; kk < 2; ++kk)                                             \
      _Pragma("unroll")                                                        \
      for (int mt = 0; mt < 4; ++mt)                                           \
        _Pragma("unroll")                                                      \
        for (int nt = 0; nt < 2; ++nt)                                         \
          acc[(mh)*4+mt][(nh)*2+nt] = __builtin_amdgcn_mfma_f32_16x16x32_bf16( \
              aF[mt][kk], bF[(nh)*2+nt][kk], acc[(mh)*4+mt][(nh)*2+nt], 0,0,0);\
    __builtin_amdgcn_s_setprio(0);                                             \
  } while (0)

  STAGEH(A,  m0,       0, 0);
  STAGEH(A,  m0 + 128, 0, 16384);
  STAGEH(Bt, n0,       0, 32768);
  STAGEH(Bt, n0 + 128, 0, 49152);
  STAGEH(Bt, n0,       64, 65536 + 32768);
  STAGEH(Bt, n0 + 128, 64, 65536 + 49152);
  asm volatile("s_waitcnt vmcnt(4)" ::: "memory");
  __builtin_amdgcn_s_barrier();

  const int NI = K >> 7;
  for (int i = 0; i < NI; ++i) {
    const int T = 2*i;
    const bool nl = (i + 1 < NI);
    const int kA1 = (T + 1) << 6;
    const int kT2 = (T + 2) << 6;
    const int kT3 = (T + 3) << 6;

#pragma unroll
    for (int kk = 0; kk < 2; ++kk) {
#pragma unroll
      for (int mt = 0; mt < 4; ++mt) aF[mt][kk] = *(const short8*)(lds + mt*2048 + aoff[kk]);
#pragma unroll
      for (int nf = 0; nf < 2; ++nf) bF[nf][kk] = *(const short8*)(lds + nf*2048 + boff[kk]);
    }
    STAGEH(A, m0, kA1, 65536);
    BAR();
    MFQ(0, 0);
    BAR();
#pragma unroll
    for (int kk = 0; kk < 2; ++kk)
#pragma unroll
      for (int nf = 2; nf < 4; ++nf) bF[nf][kk] = *(const short8*)(lds + nf*2048 + boff[kk]);
    STAGEH(A, m0 + 128, kA1, 65536 + 16384);
    BAR();
    MFQ(0, 1);
    BAR();
#pragma unroll
    for (int kk = 0; kk < 2; ++kk)
#pragma unroll
      for (int mt = 0; mt < 4; ++mt) aF[mt][kk] = *(const short8*)(lds + (4+mt)*2048 + aoff[kk]);
    if (nl) STAGEH(Bt, n0, kT2, 32768);
    BAR();
    MFQ(1, 0);
    BAR();
    if (nl) {
      STAGEH(Bt, n0 + 128, kT2, 49152);
      asm volatile("s_waitcnt vmcnt(4)" ::: "memory");
    } else {
      asm volatile("s_waitcnt vmcnt(0)" ::: "memory");
    }
    BAR();
    MFQ(1, 1);
    BAR();

#pragma unroll
    for (int kk = 0; kk < 2; ++kk) {
#pragma unroll
      for (int mt = 0; mt < 4; ++mt) aF[mt][kk] = *(const short8*)(lds + 65536 + mt*2048 + aoff[kk]);
#pragma unroll
      for (int nf = 0; nf < 2; ++nf) bF[nf][kk] = *(const short8*)(lds + 65536 + nf*2048 + boff[kk]);
    }
    if (nl) STAGEH(A, m0, kT2, 0);
    BAR();
    MFQ(0, 0);
    BAR();
#pragma unroll
    for (int kk = 0; kk < 2; ++kk)
#pragma unroll
      for (int nf = 2; nf < 4; ++nf) bF[nf][kk] = *(const short8*)(lds + 65536 + nf*2048 + boff[kk]);
    if (nl) STAGEH(A, m0 + 128, kT2, 16384);
    BAR();
    MFQ(0, 1);
    BAR();
#pragma unroll
    for (int kk = 0; kk < 2; ++kk)
#pragma unroll
      for (int mt = 0; mt < 4; ++mt) aF[mt][kk] = *(const short8*)(lds + 65536 + (4+mt)*2048 + aoff[kk]);
    if (nl) STAGEH(Bt, n0, kT3, 65536 + 32768);
    BAR();
    MFQ(1, 0);
    BAR();
    if (nl) {
      STAGEH(Bt, n0 + 128, kT3, 65536 + 49152);
      asm volatile("s_waitcnt vmcnt(4)" ::: "memory");
    }
    BAR();
    MFQ(1, 1);
    BAR();
  }

  asm volatile("s_waitcnt vmcnt(0)" ::: "memory");
  __builtin_amdgcn_s_barrier();
  float* Sw = (float*)(lds) + w*1024;
#pragma unroll
  for (int mt = 0; mt < 8; ++mt) {
#pragma unroll
    for (int nt = 0; nt < 4; ++nt)
#pragma unroll
      for (int r = 0; r < 4; ++r)
        Sw[(g*4 + r)*64 + nt*16 + lr] = acc[mt][nt][r];
#pragma unroll
    for (int rep = 0; rep < 2; ++rep) {
      const int row2 = rep*8 + (lane >> 3);
      const int colf = (lane & 7)*8;
      f32x4 a0 = *(const f32x4*)(Sw + row2*64 + colf);
      f32x4 a1 = *(const f32x4*)(Sw + row2*64 + colf + 4);
      us8 ov;
#pragma unroll
      for (int j = 0; j < 4; ++j) { ov[j] = f2b(a0[j]); ov[4+j] = f2b(a1[j]); }
      const size_t rowg = m0 + wr*128 + mt*16 + row2;
      *(us8*)(Cb + rowg * (size_t)N + (n0 + wc*64 + colf)) = ov;
    }
  }
#undef STAGEH
#undef BAR
#undef MFQ
}

// ---------------------------------------------------------------------------
// O-projection 128x128 GEMM, 2-phase double-buffered (T3-minimum recipe):
// STAGE(next) issued BEFORE compute(cur); ONE __syncthreads per K-tile
// (full vmcnt(0)+lgkmcnt(0) drain at the barrier => race-free by
// construction, unlike counted-vmcnt variants). Epilogue = LN-recon residual.
// ---------------------------------------------------------------------------
__launch_bounds__(256, 2)
__global__ void gemm_oproj(const unsigned short* __restrict__ A,
                           const unsigned short* __restrict__ Bt,
                           float* __restrict__ Cf,
                           const unsigned short* __restrict__ lnx,
                           const float* __restrict__ stats,
                           const float* __restrict__ ginv,
                           const float* __restrict__ betaq,
                           const float* __restrict__ gatep,
                           int M, int N, int K)
{
  __shared__ __attribute__((aligned(16))) char lds[65536]; // A0 B0 A1 B1 x16KB
  const int tid  = threadIdx.x;
  const int lane = tid & 63, w = tid >> 6;
  const int wr = w >> 1, wc = w & 1;
  const int g = lane >> 4, lr = lane & 15;
  const int ntile = N >> 7;
  const int nwg = gridDim.x;
  const int bid = blockIdx.x;
  const int tile = ((nwg & 7) == 0) ? ((bid & 7)*(nwg >> 3) + (bid >> 3)) : bid;
  const int m0 = (tile / ntile) << 7;
  const int n0 = (tile % ntile) << 7;

  const int lrow  = lane >> 3;
  const int lslot = (lane & 7) ^ lrow;

  f32x4 acc[4][4] = {};

  auto STAGE = [&](int buf, int k0) {
    char* Ad = lds + buf*32768;
    char* Bd = Ad + 16384;
#pragma unroll
    for (int c = 0; c < 4; ++c) {
      const int rowc = (w*4 + c)*8;
      gload_lds16(A  + (size_t)(m0 + rowc + lrow)*K + k0 + lslot*8, Ad + rowc*128);
      gload_lds16(Bt + (size_t)(n0 + rowc + lrow)*K + k0 + lslot*8, Bd + rowc*128);
    }
  };

  const int NT = K >> 6;
  STAGE(0, 0);
  __syncthreads();                 // vmcnt(0)+lgkmcnt(0) drain before barrier
  int cur = 0;
  for (int t = 0; t < NT; ++t) {
    if (t + 1 < NT) STAGE(cur ^ 1, (t + 1) << 6);   // prefetch under compute
    const char* Ab = lds + cur*32768;
    const char* Bb = Ab + 16384;
#pragma unroll
    for (int ks = 0; ks < 2; ++ks) {
      short8 af[4], bfr[4];
#pragma unroll
      for (int mt = 0; mt < 4; ++mt) {
        int row = wr*64 + mt*16 + lr;
        int slot = (ks*4 + g) ^ (row & 7);
        af[mt] = *(const short8*)(Ab + row*128 + slot*16);
      }
#pragma unroll
      for (int nt = 0; nt < 4; ++nt) {
        int row = wc*64 + nt*16 + lr;
        int slot = (ks*4 + g) ^ (row & 7);
        bfr[nt] = *(const short8*)(Bb + row*128 + slot*16);
      }
#pragma unroll
      for (int mt = 0; mt < 4; ++mt)
#pragma unroll
        for (int nt = 0; nt < 4; ++nt)
          acc[mt][nt] = __builtin_amdgcn_mfma_f32_16x16x32_bf16(af[mt], bfr[nt], acc[mt][nt], 0, 0, 0);
    }
    __syncthreads();               // drain: next-tile stage complete, reads retired
    cur ^= 1;
  }

  float* Sw = (float*)(lds) + w*1024;
  const float tg = tanhf(gatep[0]);
#pragma unroll
  for (int mt = 0; mt < 4; ++mt) {
#pragma unroll
    for (int nt = 0; nt < 4; ++nt)
#pragma unroll
      for (int r = 0; r < 4; ++r)
        Sw[(g*4 + r)*64 + nt*16 + lr] = acc[mt][nt][r];
#pragma unroll
    for (int rep = 0; rep < 4; ++rep) {
      const int row2 = rep*4 + g;
      const int colf = lr*4;
      f32x4 val = *(const f32x4*)(Sw + row2*64 + colf);
      const size_t rowg = (size_t)(m0 + wr*64 + mt*16 + row2);
      const size_t col  = (size_t)(n0 + wc*64 + colf);
      const size_t idx  = rowg * (size_t)N + col;
      const float mn = stats[rowg*2 + 0];
      const float sd = stats[rowg*2 + 1];
      us4 lnv = *(const us4*)(lnx + idx);
      f32x4 gi = *(const f32x4*)(ginv + col);
      f32x4 bt4 = *(const f32x4*)(betaq + col);
#pragma unroll
      for (int j = 0; j < 4; ++j) {
        float xr = (b2f(lnv[j]) - bt4[j]) * gi[j] * sd + mn;
        val[j] = xr + tg * val[j];
      }
      *(f32x4*)(Cf + idx) = val;
    }
  }
}

// ---------------------------------------------------------------------------
// K/V projections fused: kv=0 -> K [b][h][m][d]; kv=1 -> V^T [b][h][d][m]
// ---------------------------------------------------------------------------
__launch_bounds__(256, 2)
__global__ void gemm_kv(const unsigned short* __restrict__ ck,
                        const unsigned short* __restrict__ Wk_t,
                        const unsigned short* __restrict__ Wv_t,
                        unsigned short* __restrict__ Kb,
                        unsigned short* __restrict__ Vt)
{
  __shared__ __attribute__((aligned(16))) char As[16384];
  __shared__ __attribute__((aligned(16))) char Bs[16384];
  const int bid = blockIdx.x;
  const int kv = bid >> 4, bidl = bid & 15;
  const unsigned short* Bt = kv ? Wv_t : Wk_t;
  const int m0 = (bidl >> 2) << 7, n0 = (bidl & 3) << 7;
  const int tid  = threadIdx.x;
  const int lane = tid & 63, w = tid >> 6;
  const int wr = w >> 1, wc = w & 1;
  const int g = lane >> 4, lr = lane & 15;
  const int lrow  = lane >> 3;
  const int lslot = (lane & 7) ^ lrow;
  const int K = 768;

  f32x4 acc[4][4] = {};

  for (int k0 = 0; k0 < K; k0 += 64) {
#pragma unroll
    for (int c = 0; c < 4; ++c) {
      const int rowc = (w*4 + c)*8;
      gload_lds16(ck + (size_t)(m0 + rowc + lrow)*K + k0 + lslot*8, As + rowc*128);
      gload_lds16(Bt + (size_t)(n0 + rowc + lrow)*K + k0 + lslot*8, Bs + rowc*128);
    }
    __syncthreads();
#pragma unroll
    for (int ks = 0; ks < 2; ++ks) {
      short8 af[4], bfr[4];
#pragma unroll
      for (int mt = 0; mt < 4; ++mt) {
        int row = wr*64 + mt*16 + lr;
        int slot = (ks*4 + g) ^ (row & 7);
        af[mt] = *(const short8*)(As + row*128 + slot*16);
      }
#pragma unroll
      for (int nt = 0; nt < 4; ++nt) {
        int row = wc*64 + nt*16 + lr;
        int slot = (ks*4 + g) ^ (row & 7);
        bfr[nt] = *(const short8*)(Bs + row*128 + slot*16);
      }
#pragma unroll
      for (int mt = 0; mt < 4; ++mt)
#pragma unroll
        for (int nt = 0; nt < 4; ++nt)
          acc[mt][nt] = __builtin_amdgcn_mfma_f32_16x16x32_bf16(af[mt], bfr[nt], acc[mt][nt], 0, 0, 0);
    }
    __syncthreads();
  }

#pragma unroll
  for (int mt = 0; mt < 4; ++mt)
#pragma unroll
    for (int nt = 0; nt < 4; ++nt)
#pragma unroll
      for (int r = 0; r < 4; ++r) {
        int row = m0 + wr*64 + mt*16 + g*4 + r;
        int col = n0 + wc*64 + nt*16 + lr;
        int bb = row >> 7, mm = row & 127, hh = col >> 6, dd = col & 63;
        unsigned short val = f2b(acc[mt][nt][r]);
        if (kv == 0) Kb[(((size_t)(bb*8 + hh))*128 + mm)*64 + dd] = val;
        else         Vt[(((size_t)(bb*8 + hh))*64 + dd)*128 + mm] = val;
      }
}

// ---------------------------------------------------------------------------
// LayerNorm rows -> bf16 (+ optional per-row stats: mean, sd=1/rstd).
// ---------------------------------------------------------------------------
template<int NSEG>
DEV void ln_rows_body(const float* __restrict__ in, const float* __restrict__ gamma,
                      const float* __restrict__ beta, unsigned short* __restrict__ out,
                      int C, int blk, int tid, float* __restrict__ stats)
{
  const int lane = tid & 63;
  const size_t row = (size_t)blk*4 + (tid >> 6);
  const float* rp = in + row * (size_t)C;
  f32x4 vals[NSEG];
  float s = 0.f, sq = 0.f;
#pragma unroll
  for (int i = 0; i < NSEG; ++i) {
    f32x4 v = *(const f32x4*)(rp + (i*64 + lane)*4);
    vals[i] = v;
#pragma unroll
    for (int j = 0; j < 4; ++j) { s += v[j]; sq += v[j]*v[j]; }
  }
#pragma unroll
  for (int off = 32; off >= 1; off >>= 1) {
    s  += __shfl_xor(s, off);
    sq += __shfl_xor(sq, off);
  }
  const float invC = 1.0f / (float)C;
  float mean = s * invC;
  float var  = sq * invC - mean*mean;
  float rstd = rsqrtf(var + 1e-5f);
  if (stats && lane == 0) {
    stats[row*2 + 0] = mean;
    stats[row*2 + 1] = 1.0f / rstd;
  }
#pragma unroll
  for (int i = 0; i < NSEG; ++i) {
    int cb = (i*64 + lane)*4;
    f32x4 gm = *(const f32x4*)(gamma + cb);
    f32x4 bb = *(const f32x4*)(beta + cb);
    us4 ov;
#pragma unroll
    for (int j = 0; j < 4; ++j)
      ov[j] = f2b((vals[i][j] - mean)*rstd*gm[j] + bb[j]);
    *(us4*)(out + row * (size_t)C + cb) = ov;
  }
}

// ---------------------------------------------------------------------------
// prep: big-LN(x) [0,18432) + weight transposes [..+1792) + ln_ctx [..+128)
//       + spatial [..+32) + ginv [..+1).  Grid 20385.
// ---------------------------------------------------------------------------
__global__ void prep(const float* __restrict__ x, const float* __restrict__ gq,
                     const float* __restrict__ bq, unsigned short* __restrict__ ln_x,
                     float* __restrict__ stats, float* __restrict__ ginv,
                     const float* __restrict__ Wq, const float* __restrict__ Wk,
                     const float* __restrict__ Wv, const float* __restrict__ Wo,
                     unsigned short* __restrict__ Wq_t, unsigned short* __restrict__ Wk_t,
                     unsigned short* __restrict__ Wv_t, unsigned short* __restrict__ Wo_t,
                     const float* __restrict__ ctx, const float* __restrict__ gk,
                     const float* __restrict__ bk, unsigned short* __restrict__ ck,
                     const float* __restrict__ pos, const float* __restrict__ c2w,
                     const float* __restrict__ intr, const float* __restrict__ sls,
                     const float* __restrict__ dla,
                     float* __restrict__ u_o, float* __restrict__ v_o, float* __restrict__ bh_o,
                     float* __restrict__ iv_o, float* __restrict__ dp_o)
{
  __shared__ float tile[32][33];
  int bidx = blockIdx.x;
  if (bidx < 18432) {
    ln_rows_body<4>(x, gq, bq, ln_x, 1024, bidx, threadIdx.x, stats);
    return;
  }
  bidx -= 18432;
  if (bidx < 1792) {
    const float* src; unsigned short* dst; int R, C;
    if (bidx < 512)       { src = Wq; dst = Wq_t; R = 1024; C = 512; }
    else if (bidx < 896)  { src = Wk; dst = Wk_t; R = 768;  C = 512;  bidx -= 512; }
    else if (bidx < 1280) { src = Wv; dst = Wv_t; R = 768;  C = 512;  bidx -= 896; }
    else                  { src = Wo; dst = Wo_t; R = 512;  C = 1024; bidx -= 1280; }
    const int cb = C >> 5;
    const int bx = bidx % cb, by = bidx / cb;
    const int tx = threadIdx.x & 31, ty = threadIdx.x >> 5;
#pragma unroll
    for (int i = 0; i < 32; i += 8)
      tile[ty + i][tx] = src[(size_t)(by*32 + ty + i)*C + bx*32 + tx];
    __syncthreads();
#pragma unroll
    for (int i = 0; i < 32; i += 8)
      dst[(size_t)(bx*32 + ty + i)*R + by*32 + tx] = f2b(tile[tx][ty + i]);
    return;
  }
  bidx -= 1792;
  if (bidx < 128) {
    ln_rows_body<3>(ctx, gk, bk, ck, 768, bidx, threadIdx.x, nullptr);
    return;
  }
  bidx -= 128;
  if (bidx < 32) {
    if (threadIdx.x >= 128) return;
    const int bt = bidx;
    const int b = bt >> 3;
    const int m = threadIdx.x;
    const float* Mc = c2w + (size_t)bt*16;
    float r00=Mc[0], r01=Mc[1], r02=Mc[2],  t0=Mc[3];
    float r10=Mc[4], r11=Mc[5], r12=Mc[6],  t1=Mc[7];
    float r20=Mc[8], r21=Mc[9], r22=Mc[10], t2=Mc[11];
    float a00 = r11*r22 - r12*r21;
    float a01 = r02*r21 - r01*r22;
    float a02 = r01*r12 - r02*r11;
    float a10 = r12*r20 - r10*r22;
    float a11 = r00*r22 - r02*r20;
    float a12 = r02*r10 - r00*r12;
    float a20 = r10*r21 - r11*r20;
    float a21 = r01*r20 - r00*r21;
    float a22 = r00*r11 - r01*r10;
    float det = r00*a00 + r01*a10 + r02*a20;
    float id = 1.0f/det;
    a00*=id; a01*=id; a02*=id; a10*=id; a11*=id; a12*=id; a20*=id; a21*=id; a22*=id;
    float tv0 = -(a00*t0 + a01*t1 + a02*t2);
    float tv1 = -(a10*t0 + a11*t1 + a12*t2);
    float tv2 = -(a20*t0 + a21*t1 + a22*t2);
    const float* pm = pos + (size_t)(b*128 + m)*3;
    float px = pm[0], py = pm[1], pz = pm[2];
    float xx = a00*px + a01*py + a02*pz + tv0;
    float yy = a10*px + a11*py + a12*pz + tv1;
    float zraw = a20*px + a21*py + a22*pz + tv2;
    float z = fmaxf(zraw, 1e-4f);
    float fx = intr[b*9 + 0], fy = intr[b*9 + 4], cx = intr[b*9 + 2], cy = intr[b*9 + 5];
    u_o[bt*128 + m] = fx*(xx/z) + cx;
    v_o[bt*128 + m] = fy*(yy/z) + cy;
    bh_o[bt*128 + m] = (zraw <= 0.0f) ? 1.0f : 0.0f;
    float lz = __logf(z);
#pragma unroll
    for (int hh = 0; hh < 8; ++hh) {
      float sg = __expf(sls[hh]);
      iv_o[(size_t)(bt*8 + hh)*128 + m] = z*z / (2.0f*sg*sg + 1e-8f);
      dp_o[(size_t)(bt*8 + hh)*128 + m] = dla[hh] * (-lz);
    }
    return;
  }
#pragma unroll
  for (int i = 0; i < 4; ++i) {
    int c = i*256 + threadIdx.x;
    ginv[c] = 1.0f / gq[c];
  }
}

// ---------------------------------------------------------------------------
// Fused attention: per block = (bt, h, ptile of 128). 4 waves x 32 q-rows.
// ---------------------------------------------------------------------------
__launch_bounds__(256, 2)
__global__ void attn_kernel(const unsigned short* __restrict__ q,
                            const unsigned short* __restrict__ Kb,
                            const unsigned short* __restrict__ Vt,
                            const float* __restrict__ ub, const float* __restrict__ vb,
                            const float* __restrict__ bhb,
                            const float* __restrict__ ivb, const float* __restrict__ dpb,
                            const float* __restrict__ sgate,
                            unsigned short* __restrict__ out)
{
  const int bid = blockIdx.x;
  const int ptile = bid % 18;
  const int h  = (bid / 18) & 7;
  const int bt = bid / (18*8);
  const int b  = bt >> 3;
  const int lane = threadIdx.x & 63, w = threadIdx.x >> 6;
  const int g = lane >> 4, lr = lane & 15;
  const int p0 = ptile*128 + w*32;

  const float sg = tanhf(sgate[0]);
  const unsigned short* Kh = Kb + ((size_t)(b*8 + h)) * (128*64);
  const unsigned short* Vh = Vt + ((size_t)(b*8 + h)) * (64*128);
  const unsigned short* qh = q + (size_t)bt*2304*512 + h*64;

  short8 qf[2][2];
#pragma unroll
  for (int pt = 0; pt < 2; ++pt)
#pragma unroll
    for (int ks = 0; ks < 2; ++ks)
      qf[pt][ks] = *(const short8*)(qh + (size_t)(p0 + pt*16 + lr)*512 + ks*32 + g*8);

  f32x4 st[8][2] = {};
#pragma unroll
  for (int mt = 0; mt < 8; ++mt) {
#pragma unroll
    for (int ks = 0; ks < 2; ++ks) {
      short8 kf = *(const short8*)(Kh + (mt*16 + lr)*64 + ks*32 + g*8);
#pragma unroll
      for (int pt = 0; pt < 2; ++pt)
        st[mt][pt] = __builtin_amdgcn_mfma_f32_16x16x32_bf16(kf, qf[pt][ks], st[mt][pt], 0, 0, 0);
    }
  }

  float gx[2], gy[2];
#pragma unroll
  for (int pt = 0; pt < 2; ++pt) {
    int p = p0 + pt*16 + lr;
    int py = p / 48, px = p - py*48;
    gx[pt] = (px + 0.5f) * (1.0f/48.0f);
    gy[pt] = (py + 0.5f) * (1.0f/48.0f);
  }
  const float* uB = ub  + bt*128;
  const float* vB = vb  + bt*128;
  const float* bB = bhb + bt*128;
  const float* iB = ivb + (size_t)(bt*8 + h)*128;
  const float* dB = dpb + (size_t)(bt*8 + h)*128;

  float pmax[2] = {-3.0e38f, -3.0e38f};
#pragma unroll
  for (int mt = 0; mt < 8; ++mt) {
    int mb = mt*16 + g*4;
    f32x4 uu = *(const f32x4*)(uB + mb);
    f32x4 vv = *(const f32x4*)(vB + mb);
    f32x4 bh = *(const f32x4*)(bB + mb);
    f32x4 iv = *(const f32x4*)(iB + mb);
    f32x4 dp = *(const f32x4*)(dB + mb);
#pragma unroll
    for (int r = 0; r < 4; ++r) {
#pragma unroll
      for (int pt = 0; pt < 2; ++pt) {
        float du = gx[pt] - uu[r], dv = gy[pt] - vv[r];
        float bias = (bh[r] != 0.0f) ? 0.0f : (-(du*du + dv*dv)*iv[r] + dp[r]);
        float s = st[mt][pt][r]*0.125f + sg*bias;
        st[mt][pt][r] = s;
        pmax[pt] = fmaxf(pmax[pt], s);
      }
    }
  }
#pragma unroll
  for (int pt = 0; pt < 2; ++pt) {
    pmax[pt] = fmaxf(pmax[pt], __shfl_xor(pmax[pt], 16));
    pmax[pt] = fmaxf(pmax[pt], __shfl_xor(pmax[pt], 32));
  }
  float psum[2] = {0.f, 0.f};
#pragma unroll
  for (int mt = 0; mt < 8; ++mt)
#pragma unroll
    for (int pt = 0; pt < 2; ++pt)
#pragma unroll
      for (int r = 0; r < 4; ++r) {
        float e = __expf(st[mt][pt][r] - pmax[pt]);
        st[mt][pt][r] = e;
        psum[pt] += e;
      }
#pragma unroll
  for (int pt = 0; pt < 2; ++pt) {
    psum[pt] += __shfl_xor(psum[pt], 16);
    psum[pt] += __shfl_xor(psum[pt], 32);
  }
  float pinv[2] = {1.0f/psum[0], 1.0f/psum[1]};

  short8 pf[2][4];
#pragma unroll
  for (int pt = 0; pt < 2; ++pt)
#pragma unroll
    for (int ms = 0; ms < 4; ++ms)
#pragma unroll
      for (int i = 0; i < 8; ++i)
        pf[pt][ms][i] = (short)f2b(st[ms*2 + (i>>2)][pt][i & 3] * pinv[pt]);

  f32x4 o[4][2] = {};
#pragma unroll
  for (int ms = 0; ms < 4; ++ms) {
#pragma unroll
    for (int dt = 0; dt < 4; ++dt) {
      const unsigned short* vp = Vh + (size_t)(dt*16 + lr)*128 + ms*32 + g*4;
      us4 v0 = *(const us4*)(vp);
      us4 v1 = *(const us4*)(vp + 16);
      short8 vf;
#pragma unroll
      for (int i = 0; i < 4; ++i) { vf[i] = (short)v0[i]; vf[i+4] = (short)v1[i]; }
#pragma unroll
      for (int pt = 0; pt < 2; ++pt)
        o[dt][pt] = __builtin_amdgcn_mfma_f32_16x16x32_bf16(vf, pf[pt][ms], o[dt][pt], 0, 0, 0);
    }
  }

#pragma unroll
  for (int dt = 0; dt < 4; ++dt)
#pragma unroll
    for (int pt = 0; pt < 2; ++pt) {
      int p = p0 + pt*16 + lr;
      int d = h*64 + dt*16 + g*4;
      us4 ov;
#pragma unroll
      for (int r = 0; r < 4; ++r) ov[r] = f2b(o[dt][pt][r]);
      *(us4*)(out + (size_t)(bt*2304 + p)*512 + d) = ov;
    }
}

// ---------------------------------------------------------------------------
extern "C" void kernel_launch(void* const* d_in, const int* in_sizes, int n_in,
                              void* d_out, int out_size, void* d_ws, size_t ws_size,
                              hipStream_t stream)
{
  const float* x     = (const float*)d_in[0];
  const float* ctx   = (const float*)d_in[1];
  const float* pos   = (const float*)d_in[2];
  const float* c2w   = (const float*)d_in[3];
  const float* intr  = (const float*)d_in[4];
  const float* Wq    = (const float*)d_in[5];
  const float* Wk    = (const float*)d_in[6];
  const float* Wv    = (const float*)d_in[7];
  const float* Wo    = (const float*)d_in[8];
  const float* gate  = (const float*)d_in[9];
  const float* sgate = (const float*)d_in[10];
  const float* sls   = (const float*)d_in[11];
  const float* dla   = (const float*)d_in[12];
  const float* gq    = (const float*)d_in[13];
  const float* bq    = (const float*)d_in[14];
  const float* gk    = (const float*)d_in[15];
  const float* bk    = (const float*)d_in[16];

  char* ws = (char*)d_ws;
  size_t off = 0;
  auto alloc = [&](size_t bytes) {
    char* p = ws + off;
    off += (bytes + 255) & ~(size_t)255;
    return p;
  };
  unsigned short* ln_x     = (unsigned short*)alloc(73728ull*1024*2); // persists to O-proj
  unsigned short* attn_out = (unsigned short*)alloc(73728ull*512*2);
  unsigned short* qbuf     = (unsigned short*)alloc(73728ull*512*2);
  float*          stats    = (float*)alloc(73728ull*2*4);
  float*          ginv     = (float*)alloc(1024*4);
  unsigned short* Wq_t  = (unsigned short*)alloc(512ull*1024*2);
  unsigned short* Wk_t  = (unsigned short*)alloc(512ull*768*2);
  unsigned short* Wv_t  = (unsigned short*)alloc(512ull*768*2);
  unsigned short* Wo_t  = (unsigned short*)alloc(1024ull*512*2);
  unsigned short* ck    = (unsigned short*)alloc(512ull*768*2);
  unsigned short* Kbuf  = (unsigned short*)alloc(4ull*8*128*64*2);
  unsigned short* Vtb   = (unsigned short*)alloc(4ull*8*64*128*2);
  float* u_o  = (float*)alloc(32*128*4);
  float* v_o  = (float*)alloc(32*128*4);
  float* bh_o = (float*)alloc(32*128*4);
  float* iv_o = (float*)alloc(32ull*8*128*4);
  float* dp_o = (float*)alloc(32ull*8*128*4);

  // big-LN + transposes + ln(ctx) + spatial + ginv, one launch
  prep<<<20385, 256, 0, stream>>>(x, gq, bq, ln_x, stats, ginv,
                                  Wq, Wk, Wv, Wo, Wq_t, Wk_t, Wv_t, Wo_t,
                                  ctx, gk, bk, ck,
                                  pos, c2w, intr, sls, dla,
                                  u_o, v_o, bh_o, iv_o, dp_o);

  // K/V projections -> K [b][h][m][d], V^T [b][h][d][m]
  gemm_kv<<<32, 256, 0, stream>>>(ck, Wk_t, Wv_t, Kbuf, Vtb);

  // Q projection (73728x512x1024), 8-phase 256^2 kernel
  gemm256_8ph<<<(73728/256)*(512/256), 512, 0, stream>>>(ln_x, Wq_t, qbuf, 73728, 512, 1024);

  // fused attention
  attn_kernel<<<32*8*18, 256, 0, stream>>>(qbuf, Kbuf, Vtb, u_o, v_o, bh_o, iv_o, dp_o, sgate, attn_out);

  // O-projection: 2-phase dbuf 128^2 + LN-recon residual (73728x1024x512)
  gemm_oproj<<<(73728/128)*(1024/128), 256, 0, stream>>>(attn_out, Wo_t, (float*)d_out,
                                                         ln_x, stats, ginv, bq, gate,
                                                         73728, 1024, 512);
}

// Round 11
// 493.966 us; speedup vs baseline: 1.0376x; 1.0376x over previous
//
#include <hip/hip_runtime.h>
#include <hip/hip_bf16.h>
#include <stdint.h>
#include <cstddef>

typedef short short8 __attribute__((ext_vector_type(8)));
typedef float f32x4 __attribute__((ext_vector_type(4)));
typedef unsigned short us4 __attribute__((ext_vector_type(4)));
typedef unsigned short us8 __attribute__((ext_vector_type(8)));

#define DEV static __device__ __forceinline__

DEV unsigned short f2b(float f) {
  __hip_bfloat16 h = __float2bfloat16(f);
  return __builtin_bit_cast(unsigned short, h);
}

DEV void gload_lds16(const void* g, void* lds) {
  __builtin_amdgcn_global_load_lds((const __attribute__((address_space(1))) unsigned int*)g,
                                   (__attribute__((address_space(3))) unsigned int*)lds, 16, 0, 0);
}

// ---------------------------------------------------------------------------
// 256x256 bf16 GEMM, 8-phase HK-style schedule (T2+T3+T4+T5).
// C[M][N] bf16 = A[M][K] * Bt[N][K]^T. 512 thr = 8 waves (2M x 4N),
// per-wave output 128x64. LDS 128KB = 2buf x {A,B} x 2 halves(128x64 bf16).
// Phase = {ds-read quadrant frags | stage 1 half-tile | bar | prio1 |
//          16 MFMA | prio0 | bar}. vmcnt(4) at phases 4/8 only.
// Replay-proven (R5-R9 passing builds).
// ---------------------------------------------------------------------------
__launch_bounds__(512, 2)
__global__ void gemm256_8ph(const unsigned short* __restrict__ A,
                            const unsigned short* __restrict__ Bt,
                            unsigned short* __restrict__ Cb,
                            int M, int N, int K)
{
  __shared__ __attribute__((aligned(16))) char lds[131072];
  const int tid = threadIdx.x;
  const int lane = tid & 63, w = tid >> 6;
  const int wr = w >> 2, wc = w & 3;
  const int g = lane >> 4, lr = lane & 15;
  const int ntile = N >> 8;
  const int nwg = gridDim.x;
  const int bid = blockIdx.x;
  const int tile = ((nwg & 7) == 0) ? ((bid & 7)*(nwg >> 3) + (bid >> 3)) : bid;
  const size_t m0 = (size_t)(tile / ntile) << 8;
  const size_t n0 = (size_t)(tile % ntile) << 8;

  const int srl = tid >> 3;
  const int sgc = ((tid & 7) ^ (srl & 7)) * 8;

#define STAGEH(X, grow0, k0, ldsoff)                                           \
  do {                                                                         \
    char* hb_ = lds + (ldsoff) + w*1024;                                       \
    gload_lds16((X) + ((grow0) + srl)*(size_t)K + (k0) + sgc, hb_);            \
    gload_lds16((X) + ((grow0) + 64 + srl)*(size_t)K + (k0) + sgc, hb_ + 8192);\
  } while (0)

#define BAR() do { __builtin_amdgcn_sched_barrier(0); __builtin_amdgcn_s_barrier(); __builtin_amdgcn_sched_barrier(0); } while (0)

  f32x4 acc[8][4] = {};
  short8 aF[4][2], bF[4][2];

  int aoff[2], boff[2];
#pragma unroll
  for (int kk = 0; kk < 2; ++kk) {
    const int sl = (((kk*4 + g) ^ (lr & 7)) * 16);
    aoff[kk] = wr*16384 + lr*128 + sl;
    boff[kk] = 32768 + (wc >> 1)*16384 + ((wc & 1)*64 + lr)*128 + sl;
  }

#define MFQ(mh, nh)                                                            \
  do {                                                                         \
    __builtin_amdgcn_s_setprio(1);                                             \
    _Pragma("unroll")                                                          \
    for (int kk = 0; kk < 2; ++kk)                                             \
      _Pragma("unroll")                                                        \
      for (int mt = 0; mt < 4; ++mt)                                           \
        _Pragma("unroll")                                                      \
        for (int nt = 0; nt < 2; ++nt)                                         \
          acc[(mh)*4+mt][(nh)*2+nt] = __builtin_amdgcn_mfma_f32_16x16x32_bf16( \
              aF[mt][kk], bF[(nh)*2+nt][kk], acc[(mh)*4+mt][(nh)*2+nt], 0,0,0);\
    __builtin_amdgcn_s_setprio(0);                                             \
  } while (0)

  STAGEH(A,  m0,       0, 0);
  STAGEH(A,  m0 + 128, 0, 16384);
  STAGEH(Bt, n0,       0, 32768);
  STAGEH(Bt, n0 + 128, 0, 49152);
  STAGEH(Bt, n0,       64, 65536 + 32768);
  STAGEH(Bt, n0 + 128, 64, 65536 + 49152);
  asm volatile("s_waitcnt vmcnt(4)" ::: "memory");
  __builtin_amdgcn_s_barrier();

  const int NI = K >> 7;
  for (int i = 0; i < NI; ++i) {
    const int T = 2*i;
    const bool nl = (i + 1 < NI);
    const int kA1 = (T + 1) << 6;
    const int kT2 = (T + 2) << 6;
    const int kT3 = (T + 3) << 6;

#pragma unroll
    for (int kk = 0; kk < 2; ++kk) {
#pragma unroll
      for (int mt = 0; mt < 4; ++mt) aF[mt][kk] = *(const short8*)(lds + mt*2048 + aoff[kk]);
#pragma unroll
      for (int nf = 0; nf < 2; ++nf) bF[nf][kk] = *(const short8*)(lds + nf*2048 + boff[kk]);
    }
    STAGEH(A, m0, kA1, 65536);
    BAR();
    MFQ(0, 0);
    BAR();
#pragma unroll
    for (int kk = 0; kk < 2; ++kk)
#pragma unroll
      for (int nf = 2; nf < 4; ++nf) bF[nf][kk] = *(const short8*)(lds + nf*2048 + boff[kk]);
    STAGEH(A, m0 + 128, kA1, 65536 + 16384);
    BAR();
    MFQ(0, 1);
    BAR();
#pragma unroll
    for (int kk = 0; kk < 2; ++kk)
#pragma unroll
      for (int mt = 0; mt < 4; ++mt) aF[mt][kk] = *(const short8*)(lds + (4+mt)*2048 + aoff[kk]);
    if (nl) STAGEH(Bt, n0, kT2, 32768);
    BAR();
    MFQ(1, 0);
    BAR();
    if (nl) {
      STAGEH(Bt, n0 + 128, kT2, 49152);
      asm volatile("s_waitcnt vmcnt(4)" ::: "memory");
    } else {
      asm volatile("s_waitcnt vmcnt(0)" ::: "memory");
    }
    BAR();
    MFQ(1, 1);
    BAR();

#pragma unroll
    for (int kk = 0; kk < 2; ++kk) {
#pragma unroll
      for (int mt = 0; mt < 4; ++mt) aF[mt][kk] = *(const short8*)(lds + 65536 + mt*2048 + aoff[kk]);
#pragma unroll
      for (int nf = 0; nf < 2; ++nf) bF[nf][kk] = *(const short8*)(lds + 65536 + nf*2048 + boff[kk]);
    }
    if (nl) STAGEH(A, m0, kT2, 0);
    BAR();
    MFQ(0, 0);
    BAR();
#pragma unroll
    for (int kk = 0; kk < 2; ++kk)
#pragma unroll
      for (int nf = 2; nf < 4; ++nf) bF[nf][kk] = *(const short8*)(lds + 65536 + nf*2048 + boff[kk]);
    if (nl) STAGEH(A, m0 + 128, kT2, 16384);
    BAR();
    MFQ(0, 1);
    BAR();
#pragma unroll
    for (int kk = 0; kk < 2; ++kk)
#pragma unroll
      for (int mt = 0; mt < 4; ++mt) aF[mt][kk] = *(const short8*)(lds + 65536 + (4+mt)*2048 + aoff[kk]);
    if (nl) STAGEH(Bt, n0, kT3, 65536 + 32768);
    BAR();
    MFQ(1, 0);
    BAR();
    if (nl) {
      STAGEH(Bt, n0 + 128, kT3, 65536 + 49152);
      asm volatile("s_waitcnt vmcnt(4)" ::: "memory");
    }
    BAR();
    MFQ(1, 1);
    BAR();
  }

  // epilogue: per-wave LDS retile -> us8 coalesced bf16 stores
  asm volatile("s_waitcnt vmcnt(0)" ::: "memory");
  __builtin_amdgcn_s_barrier();
  float* Sw = (float*)(lds) + w*1024;
#pragma unroll
  for (int mt = 0; mt < 8; ++mt) {
#pragma unroll
    for (int nt = 0; nt < 4; ++nt)
#pragma unroll
      for (int r = 0; r < 4; ++r)
        Sw[(g*4 + r)*64 + nt*16 + lr] = acc[mt][nt][r];
#pragma unroll
    for (int rep = 0; rep < 2; ++rep) {
      const int row2 = rep*8 + (lane >> 3);
      const int colf = (lane & 7)*8;
      f32x4 a0 = *(const f32x4*)(Sw + row2*64 + colf);
      f32x4 a1 = *(const f32x4*)(Sw + row2*64 + colf + 4);
      us8 ov;
#pragma unroll
      for (int j = 0; j < 4; ++j) { ov[j] = f2b(a0[j]); ov[4+j] = f2b(a1[j]); }
      const size_t rowg = m0 + wr*128 + mt*16 + row2;
      *(us8*)(Cb + rowg * (size_t)N + (n0 + wc*64 + colf)) = ov;
    }
  }
#undef STAGEH
#undef BAR
#undef MFQ
}

// ---------------------------------------------------------------------------
// 128x128 bf16 GEMM (proven m97-style), EPI==1: Cf = xres + tanh(gate)*C.
// Serial staging, 32KB LDS: best-measured O-projection variant (R5, 496us).
// ---------------------------------------------------------------------------
template<int EPI>
__launch_bounds__(256, 2)
__global__ void gemm_bt(const unsigned short* __restrict__ A,
                        const unsigned short* __restrict__ Bt,
                        unsigned short* __restrict__ Cb,
                        float* __restrict__ Cf,
                        const float* __restrict__ xres,
                        const float* __restrict__ gatep,
                        int M, int N, int K)
{
  __shared__ __attribute__((aligned(16))) char As[16384];
  __shared__ __attribute__((aligned(16))) char Bs[16384];
  const int tid  = threadIdx.x;
  const int lane = tid & 63, w = tid >> 6;
  const int wr = w >> 1, wc = w & 1;
  const int g = lane >> 4, lr = lane & 15;
  const int ntile = N >> 7;
  const int nwg = gridDim.x;
  const int bid = blockIdx.x;
  const int tile = ((nwg & 7) == 0) ? ((bid & 7)*(nwg >> 3) + (bid >> 3)) : bid;
  const int m0 = (tile / ntile) << 7;
  const int n0 = (tile % ntile) << 7;

  const int lrow  = lane >> 3;
  const int lslot = (lane & 7) ^ lrow;

  f32x4 acc[4][4] = {};

  for (int k0 = 0; k0 < K; k0 += 64) {
#pragma unroll
    for (int c = 0; c < 4; ++c) {
      const int rowc = (w*4 + c)*8;
      gload_lds16(A  + (size_t)(m0 + rowc + lrow)*K + k0 + lslot*8, As + rowc*128);
      gload_lds16(Bt + (size_t)(n0 + rowc + lrow)*K + k0 + lslot*8, Bs + rowc*128);
    }
    __syncthreads();
#pragma unroll
    for (int ks = 0; ks < 2; ++ks) {
      short8 af[4], bfr[4];
#pragma unroll
      for (int mt = 0; mt < 4; ++mt) {
        int row = wr*64 + mt*16 + lr;
        int slot = (ks*4 + g) ^ (row & 7);
        af[mt] = *(const short8*)(As + row*128 + slot*16);
      }
#pragma unroll
      for (int nt = 0; nt < 4; ++nt) {
        int row = wc*64 + nt*16 + lr;
        int slot = (ks*4 + g) ^ (row & 7);
        bfr[nt] = *(const short8*)(Bs + row*128 + slot*16);
      }
#pragma unroll
      for (int mt = 0; mt < 4; ++mt)
#pragma unroll
        for (int nt = 0; nt < 4; ++nt)
          acc[mt][nt] = __builtin_amdgcn_mfma_f32_16x16x32_bf16(af[mt], bfr[nt], acc[mt][nt], 0, 0, 0);
    }
    __syncthreads();
  }

  float* Sw = (float*)(As) + w*1024;
  if (EPI == 1) {
    const float tg = tanhf(gatep[0]);
#pragma unroll
    for (int mt = 0; mt < 4; ++mt) {
#pragma unroll
      for (int nt = 0; nt < 4; ++nt)
#pragma unroll
        for (int r = 0; r < 4; ++r)
          Sw[(g*4 + r)*64 + nt*16 + lr] = acc[mt][nt][r];
#pragma unroll
      for (int rep = 0; rep < 4; ++rep) {
        int row2 = rep*4 + g;
        int colf = lr*4;
        f32x4 val = *(const f32x4*)(Sw + row2*64 + colf);
        size_t rowg = (size_t)(m0 + wr*64 + mt*16 + row2);
        size_t idx = rowg * (size_t)N + (n0 + wc*64 + colf);
        f32x4 xv = *(const f32x4*)(xres + idx);
#pragma unroll
        for (int j = 0; j < 4; ++j) val[j] = xv[j] + tg*val[j];
        *(f32x4*)(Cf + idx) = val;
      }
    }
  } else {
#pragma unroll
    for (int mt = 0; mt < 4; ++mt) {
#pragma unroll
      for (int nt = 0; nt < 4; ++nt)
#pragma unroll
        for (int r = 0; r < 4; ++r)
          Sw[(g*4 + r)*64 + nt*16 + lr] = acc[mt][nt][r];
#pragma unroll
      for (int rep = 0; rep < 2; ++rep) {
        int row2 = rep*8 + (lane >> 3);
        int colf = (lane & 7)*8;
        f32x4 a0 = *(const f32x4*)(Sw + row2*64 + colf);
        f32x4 a1 = *(const f32x4*)(Sw + row2*64 + colf + 4);
        us8 ov;
#pragma unroll
        for (int j = 0; j < 4; ++j) { ov[j] = f2b(a0[j]); ov[4+j] = f2b(a1[j]); }
        size_t rowg = (size_t)(m0 + wr*64 + mt*16 + row2);
        *(us8*)(Cb + rowg * (size_t)N + (n0 + wc*64 + colf)) = ov;
      }
    }
  }
}

// ---------------------------------------------------------------------------
// K/V projections fused: kv=0 -> K layout [b][h][m][d]; kv=1 -> V^T [b][h][d][m]
// ---------------------------------------------------------------------------
__launch_bounds__(256, 2)
__global__ void gemm_kv(const unsigned short* __restrict__ ck,
                        const unsigned short* __restrict__ Wk_t,
                        const unsigned short* __restrict__ Wv_t,
                        unsigned short* __restrict__ Kb,
                        unsigned short* __restrict__ Vt)
{
  __shared__ __attribute__((aligned(16))) char As[16384];
  __shared__ __attribute__((aligned(16))) char Bs[16384];
  const int bid = blockIdx.x;
  const int kv = bid >> 4, bidl = bid & 15;
  const unsigned short* Bt = kv ? Wv_t : Wk_t;
  const int m0 = (bidl >> 2) << 7, n0 = (bidl & 3) << 7;
  const int tid  = threadIdx.x;
  const int lane = tid & 63, w = tid >> 6;
  const int wr = w >> 1, wc = w & 1;
  const int g = lane >> 4, lr = lane & 15;
  const int lrow  = lane >> 3;
  const int lslot = (lane & 7) ^ lrow;
  const int K = 768;

  f32x4 acc[4][4] = {};

  for (int k0 = 0; k0 < K; k0 += 64) {
#pragma unroll
    for (int c = 0; c < 4; ++c) {
      const int rowc = (w*4 + c)*8;
      gload_lds16(ck + (size_t)(m0 + rowc + lrow)*K + k0 + lslot*8, As + rowc*128);
      gload_lds16(Bt + (size_t)(n0 + rowc + lrow)*K + k0 + lslot*8, Bs + rowc*128);
    }
    __syncthreads();
#pragma unroll
    for (int ks = 0; ks < 2; ++ks) {
      short8 af[4], bfr[4];
#pragma unroll
      for (int mt = 0; mt < 4; ++mt) {
        int row = wr*64 + mt*16 + lr;
        int slot = (ks*4 + g) ^ (row & 7);
        af[mt] = *(const short8*)(As + row*128 + slot*16);
      }
#pragma unroll
      for (int nt = 0; nt < 4; ++nt) {
        int row = wc*64 + nt*16 + lr;
        int slot = (ks*4 + g) ^ (row & 7);
        bfr[nt] = *(const short8*)(Bs + row*128 + slot*16);
      }
#pragma unroll
      for (int mt = 0; mt < 4; ++mt)
#pragma unroll
        for (int nt = 0; nt < 4; ++nt)
          acc[mt][nt] = __builtin_amdgcn_mfma_f32_16x16x32_bf16(af[mt], bfr[nt], acc[mt][nt], 0, 0, 0);
    }
    __syncthreads();
  }

#pragma unroll
  for (int mt = 0; mt < 4; ++mt)
#pragma unroll
    for (int nt = 0; nt < 4; ++nt)
#pragma unroll
      for (int r = 0; r < 4; ++r) {
        int row = m0 + wr*64 + mt*16 + g*4 + r;
        int col = n0 + wc*64 + nt*16 + lr;
        int bb = row >> 7, mm = row & 127, hh = col >> 6, dd = col & 63;
        unsigned short val = f2b(acc[mt][nt][r]);
        if (kv == 0) Kb[(((size_t)(bb*8 + hh))*128 + mm)*64 + dd] = val;
        else         Vt[(((size_t)(bb*8 + hh))*64 + dd)*128 + mm] = val;
      }
}

// ---------------------------------------------------------------------------
// LayerNorm rows -> bf16.  One wave per row; C = NSEG*256.
// ---------------------------------------------------------------------------
template<int NSEG>
DEV void ln_rows_body(const float* __restrict__ in, const float* __restrict__ gamma,
                      const float* __restrict__ beta, unsigned short* __restrict__ out,
                      int C, int blk, int tid)
{
  const int lane = tid & 63;
  const size_t row = (size_t)blk*4 + (tid >> 6);
  const float* rp = in + row * (size_t)C;
  f32x4 vals[NSEG];
  float s = 0.f, sq = 0.f;
#pragma unroll
  for (int i = 0; i < NSEG; ++i) {
    f32x4 v = *(const f32x4*)(rp + (i*64 + lane)*4);
    vals[i] = v;
#pragma unroll
    for (int j = 0; j < 4; ++j) { s += v[j]; sq += v[j]*v[j]; }
  }
#pragma unroll
  for (int off = 32; off >= 1; off >>= 1) {
    s  += __shfl_xor(s, off);
    sq += __shfl_xor(sq, off);
  }
  const float invC = 1.0f / (float)C;
  float mean = s * invC;
  float var  = sq * invC - mean*mean;
  float rstd = rsqrtf(var + 1e-5f);
#pragma unroll
  for (int i = 0; i < NSEG; ++i) {
    int cb = (i*64 + lane)*4;
    f32x4 gm = *(const f32x4*)(gamma + cb);
    f32x4 bb = *(const f32x4*)(beta + cb);
    us4 ov;
#pragma unroll
    for (int j = 0; j < 4; ++j)
      ov[j] = f2b((vals[i][j] - mean)*rstd*gm[j] + bb[j]);
    *(us4*)(out + row * (size_t)C + cb) = ov;
  }
}

__global__ void ln_big(const float* __restrict__ in, const float* __restrict__ gamma,
                       const float* __restrict__ beta, unsigned short* __restrict__ out)
{
  ln_rows_body<4>(in, gamma, beta, out, 1024, blockIdx.x, threadIdx.x);
}

// ---------------------------------------------------------------------------
// prep: weight transposes (0..1791) + ln_ctx (1792..1919) + spatial (1920..1951)
// ---------------------------------------------------------------------------
__global__ void prep(const float* __restrict__ Wq, const float* __restrict__ Wk,
                     const float* __restrict__ Wv, const float* __restrict__ Wo,
                     unsigned short* __restrict__ Wq_t, unsigned short* __restrict__ Wk_t,
                     unsigned short* __restrict__ Wv_t, unsigned short* __restrict__ Wo_t,
                     const float* __restrict__ ctx, const float* __restrict__ gk,
                     const float* __restrict__ bk, unsigned short* __restrict__ ck,
                     const float* __restrict__ pos, const float* __restrict__ c2w,
                     const float* __restrict__ intr, const float* __restrict__ sls,
                     const float* __restrict__ dla,
                     float* __restrict__ u_o, float* __restrict__ v_o, float* __restrict__ bh_o,
                     float* __restrict__ iv_o, float* __restrict__ dp_o)
{
  __shared__ float tile[32][33];
  int bidx = blockIdx.x;
  if (bidx < 1792) {
    const float* src; unsigned short* dst; int R, C;
    if (bidx < 512)       { src = Wq; dst = Wq_t; R = 1024; C = 512; }
    else if (bidx < 896)  { src = Wk; dst = Wk_t; R = 768;  C = 512;  bidx -= 512; }
    else if (bidx < 1280) { src = Wv; dst = Wv_t; R = 768;  C = 512;  bidx -= 896; }
    else                  { src = Wo; dst = Wo_t; R = 512;  C = 1024; bidx -= 1280; }
    const int cb = C >> 5;
    const int bx = bidx % cb, by = bidx / cb;
    const int tx = threadIdx.x & 31, ty = threadIdx.x >> 5;
#pragma unroll
    for (int i = 0; i < 32; i += 8)
      tile[ty + i][tx] = src[(size_t)(by*32 + ty + i)*C + bx*32 + tx];
    __syncthreads();
#pragma unroll
    for (int i = 0; i < 32; i += 8)
      dst[(size_t)(bx*32 + ty + i)*R + by*32 + tx] = f2b(tile[tx][ty + i]);
    return;
  }
  if (bidx < 1920) {
    ln_rows_body<3>(ctx, gk, bk, ck, 768, bidx - 1792, threadIdx.x);
    return;
  }
  if (threadIdx.x >= 128) return;
  const int bt = bidx - 1920;
  const int b = bt >> 3;
  const int m = threadIdx.x;
  const float* Mc = c2w + (size_t)bt*16;
  float r00=Mc[0], r01=Mc[1], r02=Mc[2],  t0=Mc[3];
  float r10=Mc[4], r11=Mc[5], r12=Mc[6],  t1=Mc[7];
  float r20=Mc[8], r21=Mc[9], r22=Mc[10], t2=Mc[11];
  float a00 = r11*r22 - r12*r21;
  float a01 = r02*r21 - r01*r22;
  float a02 = r01*r12 - r02*r11;
  float a10 = r12*r20 - r10*r22;
  float a11 = r00*r22 - r02*r20;
  float a12 = r02*r10 - r00*r12;
  float a20 = r10*r21 - r11*r20;
  float a21 = r01*r20 - r00*r21;
  float a22 = r00*r11 - r01*r10;
  float det = r00*a00 + r01*a10 + r02*a20;
  float id = 1.0f/det;
  a00*=id; a01*=id; a02*=id; a10*=id; a11*=id; a12*=id; a20*=id; a21*=id; a22*=id;
  float tv0 = -(a00*t0 + a01*t1 + a02*t2);
  float tv1 = -(a10*t0 + a11*t1 + a12*t2);
  float tv2 = -(a20*t0 + a21*t1 + a22*t2);
  const float* pm = pos + (size_t)(b*128 + m)*3;
  float px = pm[0], py = pm[1], pz = pm[2];
  float x = a00*px + a01*py + a02*pz + tv0;
  float y = a10*px + a11*py + a12*pz + tv1;
  float zraw = a20*px + a21*py + a22*pz + tv2;
  float z = fmaxf(zraw, 1e-4f);
  float fx = intr[b*9 + 0], fy = intr[b*9 + 4], cx = intr[b*9 + 2], cy = intr[b*9 + 5];
  u_o[bt*128 + m] = fx*(x/z) + cx;
  v_o[bt*128 + m] = fy*(y/z) + cy;
  bh_o[bt*128 + m] = (zraw <= 0.0f) ? 1.0f : 0.0f;
  float lz = __logf(z);
#pragma unroll
  for (int hh = 0; hh < 8; ++hh) {
    float sg = __expf(sls[hh]);
    iv_o[(size_t)(bt*8 + hh)*128 + m] = z*z / (2.0f*sg*sg + 1e-8f);
    dp_o[(size_t)(bt*8 + hh)*128 + m] = dla[hh] * (-lz);
  }
}

// ---------------------------------------------------------------------------
// Fused attention: per block = (bt, h, ptile of 128). 4 waves x 32 q-rows.
// ---------------------------------------------------------------------------
__launch_bounds__(256, 2)
__global__ void attn_kernel(const unsigned short* __restrict__ q,
                            const unsigned short* __restrict__ Kb,
                            const unsigned short* __restrict__ Vt,
                            const float* __restrict__ ub, const float* __restrict__ vb,
                            const float* __restrict__ bhb,
                            const float* __restrict__ ivb, const float* __restrict__ dpb,
                            const float* __restrict__ sgate,
                            unsigned short* __restrict__ out)
{
  const int bid = blockIdx.x;
  const int ptile = bid % 18;
  const int h  = (bid / 18) & 7;
  const int bt = bid / (18*8);
  const int b  = bt >> 3;
  const int lane = threadIdx.x & 63, w = threadIdx.x >> 6;
  const int g = lane >> 4, lr = lane & 15;
  const int p0 = ptile*128 + w*32;

  const float sg = tanhf(sgate[0]);
  const unsigned short* Kh = Kb + ((size_t)(b*8 + h)) * (128*64);
  const unsigned short* Vh = Vt + ((size_t)(b*8 + h)) * (64*128);
  const unsigned short* qh = q + (size_t)bt*2304*512 + h*64;

  short8 qf[2][2];
#pragma unroll
  for (int pt = 0; pt < 2; ++pt)
#pragma unroll
    for (int ks = 0; ks < 2; ++ks)
      qf[pt][ks] = *(const short8*)(qh + (size_t)(p0 + pt*16 + lr)*512 + ks*32 + g*8);

  f32x4 st[8][2] = {};
#pragma unroll
  for (int mt = 0; mt < 8; ++mt) {
#pragma unroll
    for (int ks = 0; ks < 2; ++ks) {
      short8 kf = *(const short8*)(Kh + (mt*16 + lr)*64 + ks*32 + g*8);
#pragma unroll
      for (int pt = 0; pt < 2; ++pt)
        st[mt][pt] = __builtin_amdgcn_mfma_f32_16x16x32_bf16(kf, qf[pt][ks], st[mt][pt], 0, 0, 0);
    }
  }

  float gx[2], gy[2];
#pragma unroll
  for (int pt = 0; pt < 2; ++pt) {
    int p = p0 + pt*16 + lr;
    int py = p / 48, px = p - py*48;
    gx[pt] = (px + 0.5f) * (1.0f/48.0f);
    gy[pt] = (py + 0.5f) * (1.0f/48.0f);
  }
  const float* uB = ub  + bt*128;
  const float* vB = vb  + bt*128;
  const float* bB = bhb + bt*128;
  const float* iB = ivb + (size_t)(bt*8 + h)*128;
  const float* dB = dpb + (size_t)(bt*8 + h)*128;

  float pmax[2] = {-3.0e38f, -3.0e38f};
#pragma unroll
  for (int mt = 0; mt < 8; ++mt) {
    int mb = mt*16 + g*4;
    f32x4 uu = *(const f32x4*)(uB + mb);
    f32x4 vv = *(const f32x4*)(vB + mb);
    f32x4 bh = *(const f32x4*)(bB + mb);
    f32x4 iv = *(const f32x4*)(iB + mb);
    f32x4 dp = *(const f32x4*)(dB + mb);
#pragma unroll
    for (int r = 0; r < 4; ++r) {
#pragma unroll
      for (int pt = 0; pt < 2; ++pt) {
        float du = gx[pt] - uu[r], dv = gy[pt] - vv[r];
        float bias = (bh[r] != 0.0f) ? 0.0f : (-(du*du + dv*dv)*iv[r] + dp[r]);
        float s = st[mt][pt][r]*0.125f + sg*bias;
        st[mt][pt][r] = s;
        pmax[pt] = fmaxf(pmax[pt], s);
      }
    }
  }
#pragma unroll
  for (int pt = 0; pt < 2; ++pt) {
    pmax[pt] = fmaxf(pmax[pt], __shfl_xor(pmax[pt], 16));
    pmax[pt] = fmaxf(pmax[pt], __shfl_xor(pmax[pt], 32));
  }
  float psum[2] = {0.f, 0.f};
#pragma unroll
  for (int mt = 0; mt < 8; ++mt)
#pragma unroll
    for (int pt = 0; pt < 2; ++pt)
#pragma unroll
      for (int r = 0; r < 4; ++r) {
        float e = __expf(st[mt][pt][r] - pmax[pt]);
        st[mt][pt][r] = e;
        psum[pt] += e;
      }
#pragma unroll
  for (int pt = 0; pt < 2; ++pt) {
    psum[pt] += __shfl_xor(psum[pt], 16);
    psum[pt] += __shfl_xor(psum[pt], 32);
  }
  float pinv[2] = {1.0f/psum[0], 1.0f/psum[1]};

  short8 pf[2][4];
#pragma unroll
  for (int pt = 0; pt < 2; ++pt)
#pragma unroll
    for (int ms = 0; ms < 4; ++ms)
#pragma unroll
      for (int i = 0; i < 8; ++i)
        pf[pt][ms][i] = (short)f2b(st[ms*2 + (i>>2)][pt][i & 3] * pinv[pt]);

  f32x4 o[4][2] = {};
#pragma unroll
  for (int ms = 0; ms < 4; ++ms) {
#pragma unroll
    for (int dt = 0; dt < 4; ++dt) {
      const unsigned short* vp = Vh + (size_t)(dt*16 + lr)*128 + ms*32 + g*4;
      us4 v0 = *(const us4*)(vp);
      us4 v1 = *(const us4*)(vp + 16);
      short8 vf;
#pragma unroll
      for (int i = 0; i < 4; ++i) { vf[i] = (short)v0[i]; vf[i+4] = (short)v1[i]; }
#pragma unroll
      for (int pt = 0; pt < 2; ++pt)
        o[dt][pt] = __builtin_amdgcn_mfma_f32_16x16x32_bf16(vf, pf[pt][ms], o[dt][pt], 0, 0, 0);
    }
  }

#pragma unroll
  for (int dt = 0; dt < 4; ++dt)
#pragma unroll
    for (int pt = 0; pt < 2; ++pt) {
      int p = p0 + pt*16 + lr;
      int d = h*64 + dt*16 + g*4;
      us4 ov;
#pragma unroll
      for (int r = 0; r < 4; ++r) ov[r] = f2b(o[dt][pt][r]);
      *(us4*)(out + (size_t)(bt*2304 + p)*512 + d) = ov;
    }
}

// ---------------------------------------------------------------------------
extern "C" void kernel_launch(void* const* d_in, const int* in_sizes, int n_in,
                              void* d_out, int out_size, void* d_ws, size_t ws_size,
                              hipStream_t stream)
{
  const float* x     = (const float*)d_in[0];
  const float* ctx   = (const float*)d_in[1];
  const float* pos   = (const float*)d_in[2];
  const float* c2w   = (const float*)d_in[3];
  const float* intr  = (const float*)d_in[4];
  const float* Wq    = (const float*)d_in[5];
  const float* Wk    = (const float*)d_in[6];
  const float* Wv    = (const float*)d_in[7];
  const float* Wo    = (const float*)d_in[8];
  const float* gate  = (const float*)d_in[9];
  const float* sgate = (const float*)d_in[10];
  const float* sls   = (const float*)d_in[11];
  const float* dla   = (const float*)d_in[12];
  const float* gq    = (const float*)d_in[13];
  const float* bq    = (const float*)d_in[14];
  const float* gk    = (const float*)d_in[15];
  const float* bk    = (const float*)d_in[16];

  char* ws = (char*)d_ws;
  size_t off = 0;
  auto alloc = [&](size_t bytes) {
    char* p = ws + off;
    off += (bytes + 255) & ~(size_t)255;
    return p;
  };
  unsigned short* ln_x  = (unsigned short*)alloc(73728ull*1024*2); // reused as attn_out
  unsigned short* qbuf  = (unsigned short*)alloc(73728ull*512*2);
  unsigned short* Wq_t  = (unsigned short*)alloc(512ull*1024*2);
  unsigned short* Wk_t  = (unsigned short*)alloc(512ull*768*2);
  unsigned short* Wv_t  = (unsigned short*)alloc(512ull*768*2);
  unsigned short* Wo_t  = (unsigned short*)alloc(1024ull*512*2);
  unsigned short* ck    = (unsigned short*)alloc(512ull*768*2);
  unsigned short* Kbuf  = (unsigned short*)alloc(4ull*8*128*64*2);
  unsigned short* Vtb   = (unsigned short*)alloc(4ull*8*64*128*2);
  float* u_o  = (float*)alloc(32*128*4);
  float* v_o  = (float*)alloc(32*128*4);
  float* bh_o = (float*)alloc(32*128*4);
  float* iv_o = (float*)alloc(32ull*8*128*4);
  float* dp_o = (float*)alloc(32ull*8*128*4);
  unsigned short* attn_out = ln_x;

  // transposes + ln(ctx) + spatial precompute, one launch
  prep<<<1952, 256, 0, stream>>>(Wq, Wk, Wv, Wo, Wq_t, Wk_t, Wv_t, Wo_t,
                                 ctx, gk, bk, ck,
                                 pos, c2w, intr, sls, dla,
                                 u_o, v_o, bh_o, iv_o, dp_o);

  // layernorm of x -> bf16
  ln_big<<<73728/4, 256, 0, stream>>>(x, gq, bq, ln_x);

  // K/V projections -> K [b][h][m][d], V^T [b][h][d][m]
  gemm_kv<<<32, 256, 0, stream>>>(ck, Wk_t, Wv_t, Kbuf, Vtb);

  // Q projection (73728x512x1024), 8-phase 256^2 kernel
  gemm256_8ph<<<(73728/256)*(512/256), 512, 0, stream>>>(ln_x, Wq_t, qbuf, 73728, 512, 1024);

  // fused attention
  attn_kernel<<<32*8*18, 256, 0, stream>>>(qbuf, Kbuf, Vtb, u_o, v_o, bh_o, iv_o, dp_o, sgate, attn_out);

  // final projection + residual (73728x1024x512)
  gemm_bt<1><<<(73728/128)*(1024/128), 256, 0, stream>>>(attn_out, Wo_t, nullptr, (float*)d_out, x, gate, 73728, 1024, 512);
}